// Round 9
// baseline (252.914 us; speedup 1.0000x reference)
//
#include <hip/hip_runtime.h>
#include <stdint.h>

#define D_DIM   512
#define BM      64
#define THREADS 512            // 8 waves; each wave owns 64 N-cols (nt=4)
#define NBLOCKS 2048           // 131072 / 64

typedef __attribute__((ext_vector_type(8))) __bf16 bf16x8;
typedef __attribute__((ext_vector_type(4))) float  f32x4;

__device__ __forceinline__ unsigned short f32_to_bf16_rne(float f) {
    uint32_t u = __builtin_bit_cast(uint32_t, f);
    u += 0x7FFFu + ((u >> 16) & 1u);
    return (unsigned short)(u >> 16);
}

// Repack L (fp32 row-major [K=512][N=512]) into bf16 fragment order:
// flat ushort idx = ((ks*32 + ntg)*64 + lane)*8 + e  holds L[k][n],
//   n = ntg*16 + (lane&15),  k = ks*32 + (lane>>4)*8 + e.
__global__ void prep_lt(const float* __restrict__ L, unsigned short* __restrict__ Ltf) {
    int o = blockIdx.x * 256 + threadIdx.x;
    #pragma unroll
    for (int i = 0; i < 4; ++i) {
        int idx  = o + i * 65536;
        int e    = idx & 7;
        int l    = (idx >> 3) & 63;
        int tile = idx >> 9;
        int ntg  = tile & 31;
        int ks   = tile >> 5;
        int n    = ntg * 16 + (l & 15);
        int k    = ks * 32 + (l >> 4) * 8 + e;
        Ltf[idx] = f32_to_bf16_rne(L[k * 512 + n]);
    }
}

__global__ __launch_bounds__(THREADS, 4)
void psd_main(const float* __restrict__ x, const unsigned short* __restrict__ Ltf,
              const float* __restrict__ b, const float* __restrict__ c,
              float* __restrict__ out) {
    // two fp32 K-quarter slots [64 rows][128 cols]; stored 16B-unit u at row r
    // holds logical unit u ^ (r&15) (involution, bank-spreading)
    __shared__ __align__(16) float As[2][BM * 128];   // 64 KiB
    __shared__ __align__(16) float bsh[D_DIM];        // 2 KiB, b staged once
    __shared__ float wpart[8][BM];
    __shared__ float bpart[BM];

    const int t    = threadIdx.x;
    const int w    = t >> 6;          // wave 0..7
    const int lane = t & 63;
    const int g    = lane >> 4;
    const int ln   = lane & 15;
    const int lo   = lane & 31;       // stage: stored 16B unit
    const int hi   = lane >> 5;       // stage: row parity

    char* AsB = (char*)&As[0][0];
    char* bshB = (char*)&bsh[0];
    const char* xB = (const char*)x + (size_t)blockIdx.x * (BM * 2048);

    // fragment-order L base for this wave (ntg = w*4 + nt)
    const unsigned short* LtW = Ltf + (size_t)w * 2048 + (size_t)lane * 8;

    f32x4 acc[4][4];
    #pragma unroll
    for (int m = 0; m < 4; ++m)
        #pragma unroll
        for (int nt = 0; nt < 4; ++nt)
            acc[m][nt] = (f32x4){0.f, 0.f, 0.f, 0.f};
    float bacc = 0.f;

    // Stage quarter Q (fp32 cols [Q*128, Q*128+128)) into slot Q&1.
    // Wave w covers rows [w*8, w*8+8): instr j = rows w*8+2j, w*8+2j+1 (1 KB linear).
#define STAGE(Q)                                                                         \
    {                                                                                    \
        char* ldsw = AsB + ((Q) & 1) * 32768 + w * 4096;                                 \
        _Pragma("unroll")                                                                \
        for (int j = 0; j < 4; ++j) {                                                    \
            const int row = w * 8 + j * 2 + hi;                                          \
            const char* gsrc = xB + (size_t)row * 2048 + (Q) * 512                       \
                             + ((lo ^ (row & 15)) << 4);                                 \
            __builtin_amdgcn_global_load_lds(                                            \
                (const __attribute__((address_space(1))) void*)gsrc,                     \
                (__attribute__((address_space(3))) void*)(ldsw + j * 1024), 16, 0, 0);   \
        }                                                                                \
    }

    // Compute quarter Q from slot Q&1: 4 K-steps of 32; B-fragments streamed
    // with a 2-deep register ping-pong (bcur/bn).
#define COMPUTE(Q)                                                                       \
    {                                                                                    \
        const char* rb = AsB + ((Q) & 1) * 32768;                                        \
        _Pragma("unroll")                                                                \
        for (int kl = 0; kl < 4; ++kl) {                                                 \
            bf16x8 a[4];                                                                 \
            _Pragma("unroll")                                                            \
            for (int m = 0; m < 4; ++m) {                                                \
                const int row = m * 16 + ln;                                             \
                const int cb  = kl * 8 + g * 2;                                          \
                f32x4 f0 = *(const f32x4*)(rb + row * 512 + (((cb    ) ^ ln) << 4));     \
                f32x4 f1 = *(const f32x4*)(rb + row * 512 + (((cb + 1) ^ ln) << 4));     \
                a[m][0] = (__bf16)f0[0]; a[m][1] = (__bf16)f0[1];                        \
                a[m][2] = (__bf16)f0[2]; a[m][3] = (__bf16)f0[3];                        \
                a[m][4] = (__bf16)f1[0]; a[m][5] = (__bf16)f1[1];                        \
                a[m][6] = (__bf16)f1[2]; a[m][7] = (__bf16)f1[3];                        \
            }                                                                            \
            _Pragma("unroll")                                                            \
            for (int nt = 0; nt < 4; ++nt) {                                             \
                const int gn = ((Q) * 16 + kl * 4 + nt + 1) & 63;   /* next frag */      \
                bf16x8 bn = *(const bf16x8*)(LtW + (size_t)(gn >> 2) * 16384             \
                                                 + (size_t)(gn & 3) * 512);              \
                _Pragma("unroll")                                                        \
                for (int m = 0; m < 4; ++m)                                              \
                    acc[m][nt] = __builtin_amdgcn_mfma_f32_16x16x32_bf16(a[m], bcur, acc[m][nt], 0, 0, 0); \
                bcur = bn;                                                               \
            }                                                                            \
        }                                                                                \
    }

    // x.b partial from the fp32 slot; b comes from LDS (no vmcnt traffic).
    // Lane covers row w*8+(lane&7), 16B-units cw*4..cw*4+3 (cw = lane>>3).
#define XB_PASS(Q)                                                                       \
    {                                                                                    \
        const char* rb = AsB + ((Q) & 1) * 32768;                                        \
        const int r8  = lane & 7;                                                        \
        const int cw  = lane >> 3;                                                       \
        const int row = w * 8 + r8;                                                      \
        const int rsw = row & 15;                                                        \
        _Pragma("unroll")                                                                \
        for (int i = 0; i < 4; ++i) {                                                    \
            const int unit = cw * 4 + i;                                                 \
            f32x4 xv = *(const f32x4*)(rb + row * 512 + ((unit ^ rsw) << 4));            \
            f32x4 bv = *(const f32x4*)(bshB + ((Q) * 32 + unit) * 16);                   \
            bacc += xv[0] * bv[0] + xv[1] * bv[1] + xv[2] * bv[2] + xv[3] * bv[3];       \
        }                                                                                \
    }

    // ---- prologue: stage quarter 0 + b ----
    STAGE(0)
    if (w < 2) {
        const char* gsrc = (const char*)b + (size_t)t * 16;
        __builtin_amdgcn_global_load_lds(
            (const __attribute__((address_space(1))) void*)gsrc,
            (__attribute__((address_space(3))) void*)(bshB + w * 1024), 16, 0, 0);
    }
    __syncthreads();          // drains STAGE(0) + b

    bf16x8 bcur = *(const bf16x8*)(LtW);   // first B-fragment (gfi=0)

    STAGE(1)                  // flies under COMPUTE(0)
    COMPUTE(0)
    XB_PASS(0)
    __syncthreads();          // drains STAGE(1); all waves done with slot 0
    STAGE(2)
    COMPUTE(1)
    XB_PASS(1)
    __syncthreads();
    STAGE(3)
    COMPUTE(2)
    XB_PASS(2)
    __syncthreads();
    COMPUTE(3)
    XB_PASS(3)

#undef STAGE
#undef COMPUTE
#undef XB_PASS

    // rowsum of squares; C/D layout: col = lane&15, row = 4*(lane>>4) + reg
    #pragma unroll
    for (int m = 0; m < 4; ++m) {
        #pragma unroll
        for (int r = 0; r < 4; ++r) {
            float s = 0.f;
            #pragma unroll
            for (int nt = 0; nt < 4; ++nt) { float vv = acc[m][nt][r]; s += vv * vv; }
            s += __shfl_xor(s, 1);
            s += __shfl_xor(s, 2);
            s += __shfl_xor(s, 4);
            s += __shfl_xor(s, 8);
            if (ln == 0) wpart[w][m * 16 + g * 4 + r] = s;
        }
    }

    // x.b: reduce over the 8 lanes sharing a row (lane bits 3..5 = cw)
    {
        float s = bacc;
        s += __shfl_xor(s, 8);
        s += __shfl_xor(s, 16);
        s += __shfl_xor(s, 32);
        if (lane < 8) bpart[w * 8 + lane] = s;
    }
    __syncthreads();

    if (t < BM) {
        float y = c[0] + bpart[t];
        #pragma unroll
        for (int ww = 0; ww < 8; ++ww) y += wpart[ww][t];
        out[(size_t)blockIdx.x * BM + t] = y;
    }
}

extern "C" void kernel_launch(void* const* d_in, const int* in_sizes, int n_in,
                              void* d_out, int out_size, void* d_ws, size_t ws_size,
                              hipStream_t stream) {
    const float* x = (const float*)d_in[0];
    const float* L = (const float*)d_in[1];
    const float* b = (const float*)d_in[2];
    const float* c = (const float*)d_in[3];
    float* out = (float*)d_out;
    unsigned short* Ltf = (unsigned short*)d_ws;   // 512 KiB

    prep_lt<<<256, 256, 0, stream>>>(L, Ltf);
    psd_main<<<NBLOCKS, THREADS, 0, stream>>>(x, Ltf, b, c, out);
}

// Round 10
// 244.407 us; speedup vs baseline: 1.0348x; 1.0348x over previous
//
#include <hip/hip_runtime.h>
#include <stdint.h>

#define D_DIM   512
#define BM      128
#define BK      64
#define THREADS 512            // 8 waves; wave tile 128 rows x 64 cols (nt=4)
#define NBLOCKS 1024           // 131072 / 128

typedef __attribute__((ext_vector_type(8))) __bf16 bf16x8;
typedef __attribute__((ext_vector_type(4))) float  f32x4;

__device__ __forceinline__ unsigned short f32_to_bf16_rne(float f) {
    uint32_t u = __builtin_bit_cast(uint32_t, f);
    u += 0x7FFFu + ((u >> 16) & 1u);
    return (unsigned short)(u >> 16);
}

// Repack L (fp32 row-major [K=512][N=512]) into bf16 fragment order:
// flat ushort idx = ((ks*32 + ntg)*64 + lane)*8 + e  holds L[k][n],
//   n = ntg*16 + (lane&15),  k = ks*32 + (lane>>4)*8 + e.
__global__ void prep_lt(const float* __restrict__ L, unsigned short* __restrict__ Ltf) {
    int o = blockIdx.x * 256 + threadIdx.x;
    #pragma unroll
    for (int i = 0; i < 4; ++i) {
        int idx  = o + i * 65536;
        int e    = idx & 7;
        int l    = (idx >> 3) & 63;
        int tile = idx >> 9;
        int ntg  = tile & 31;
        int ks   = tile >> 5;
        int n    = ntg * 16 + (l & 15);
        int k    = ks * 32 + (l >> 4) * 8 + e;
        Ltf[idx] = f32_to_bf16_rne(L[k * 512 + n]);
    }
}

__global__ __launch_bounds__(THREADS, 2)
void psd_main(const float* __restrict__ x, const unsigned short* __restrict__ Ltf,
              const float* __restrict__ b, const float* __restrict__ c,
              float* __restrict__ out) {
    // two fp32 K-slice slots [128 rows][64 cols]; stored 16B-unit u at row r
    // holds logical unit u ^ (r&15) (involution; 16 units per 256B row)
    __shared__ __align__(16) float As[2][BM * BK];    // 2 x 32 KiB
    __shared__ __align__(16) float bsh[D_DIM];        // 2 KiB
    __shared__ float wpart[8][BM];                    // 4 KiB
    __shared__ float bpart[BM];

    const int t    = threadIdx.x;
    const int w    = t >> 6;          // wave 0..7; owns n-cols [w*64, w*64+64)
    const int lane = t & 63;
    const int g    = lane >> 4;
    const int ln   = lane & 15;

    char* AsB  = (char*)&As[0][0];
    char* bshB = (char*)&bsh[0];
    const char* xB = (const char*)x + (size_t)blockIdx.x * (BM * 2048);

    // fragment-order L base for this wave (ntg = w*4 + nt)
    const unsigned short* LtW = Ltf + (size_t)w * 2048 + (size_t)lane * 8;

    f32x4 acc[8][4];
    #pragma unroll
    for (int m = 0; m < 8; ++m)
        #pragma unroll
        for (int nt = 0; nt < 4; ++nt)
            acc[m][nt] = (f32x4){0.f, 0.f, 0.f, 0.f};
    float bacc = 0.f;

    // Stage K-slice Q (fp32 cols [Q*64, Q*64+64)) into slot Q&1.
    // Wave w covers rows [w*16, w*16+16); instr j covers rows w*16+j*4 .. +3.
    // Lane (row = w*16+j*4+(lane>>4), stored unit lane&15) fetches global
    // unit (lane&15)^(row&15); LDS dest is linear (wave-uniform base + lane*16).
#define STAGE(Q)                                                                         \
    {                                                                                    \
        char* ldsw = AsB + ((Q) & 1) * 32768 + w * 4096;                                 \
        _Pragma("unroll")                                                                \
        for (int j = 0; j < 4; ++j) {                                                    \
            const int row = w * 16 + j * 4 + (lane >> 4);                                \
            const char* gsrc = xB + (size_t)row * 2048 + (Q) * 256                       \
                             + ((ln ^ (row & 15)) << 4);                                 \
            __builtin_amdgcn_global_load_lds(                                            \
                (const __attribute__((address_space(1))) void*)gsrc,                     \
                (__attribute__((address_space(3))) void*)(ldsw + j * 1024), 16, 0, 0);   \
        }                                                                                \
    }

    // Compute K-slice Q from slot Q&1: 2 K-steps of 32.
#define COMPUTE(Q)                                                                       \
    {                                                                                    \
        const char* rb = AsB + ((Q) & 1) * 32768;                                        \
        _Pragma("unroll")                                                                \
        for (int kl = 0; kl < 2; ++kl) {                                                 \
            const int ks = (Q) * 2 + kl;                                                 \
            bf16x8 bfr[4];                                                               \
            _Pragma("unroll")                                                            \
            for (int nt = 0; nt < 4; ++nt)                                               \
                bfr[nt] = *(const bf16x8*)(LtW + (size_t)ks * 16384 + nt * 512);         \
            _Pragma("unroll")                                                            \
            for (int m = 0; m < 8; ++m) {                                                \
                const int row = m * 16 + ln;                                             \
                const int cb  = kl * 8 + g * 2;                                          \
                f32x4 f0 = *(const f32x4*)(rb + row * 256 + (((cb    ) ^ ln) << 4));     \
                f32x4 f1 = *(const f32x4*)(rb + row * 256 + (((cb + 1) ^ ln) << 4));     \
                bf16x8 a;                                                                \
                a[0] = (__bf16)f0[0]; a[1] = (__bf16)f0[1];                              \
                a[2] = (__bf16)f0[2]; a[3] = (__bf16)f0[3];                              \
                a[4] = (__bf16)f1[0]; a[5] = (__bf16)f1[1];                              \
                a[6] = (__bf16)f1[2]; a[7] = (__bf16)f1[3];                              \
                _Pragma("unroll")                                                        \
                for (int nt = 0; nt < 4; ++nt)                                           \
                    acc[m][nt] = __builtin_amdgcn_mfma_f32_16x16x32_bf16(a, bfr[nt], acc[m][nt], 0, 0, 0); \
            }                                                                            \
        }                                                                                \
    }

    // x.b partial from the fp32 slot; b from LDS. Thread covers row t>>2,
    // 16B-units (t&3)*4 .. +3 of the 16-unit slice.
#define XB_PASS(Q)                                                                       \
    {                                                                                    \
        const char* rb = AsB + ((Q) & 1) * 32768;                                        \
        const int row = t >> 2;                                                          \
        const int rsw = row & 15;                                                        \
        _Pragma("unroll")                                                                \
        for (int i = 0; i < 4; ++i) {                                                    \
            const int unit = (t & 3) * 4 + i;                                            \
            f32x4 xv = *(const f32x4*)(rb + row * 256 + ((unit ^ rsw) << 4));            \
            f32x4 bv = *(const f32x4*)(bshB + ((Q) * 16 + unit) * 16);                   \
            bacc += xv[0] * bv[0] + xv[1] * bv[1] + xv[2] * bv[2] + xv[3] * bv[3];       \
        }                                                                                \
    }

    // ---- prologue: stage slice 0 + b ----
    STAGE(0)
    if (w < 2) {
        const char* gsrc = (const char*)b + (size_t)t * 16;
        __builtin_amdgcn_global_load_lds(
            (const __attribute__((address_space(1))) void*)gsrc,
            (__attribute__((address_space(3))) void*)(bshB + w * 1024), 16, 0, 0);
    }
    __syncthreads();          // drains STAGE(0) + b

    STAGE(1)                  // flies under COMPUTE(0)
    COMPUTE(0)
    XB_PASS(0)
    __syncthreads();
    STAGE(2)
    COMPUTE(1)
    XB_PASS(1)
    __syncthreads();
    STAGE(3)
    COMPUTE(2)
    XB_PASS(2)
    __syncthreads();
    STAGE(4)
    COMPUTE(3)
    XB_PASS(3)
    __syncthreads();
    STAGE(5)
    COMPUTE(4)
    XB_PASS(4)
    __syncthreads();
    STAGE(6)
    COMPUTE(5)
    XB_PASS(5)
    __syncthreads();
    STAGE(7)
    COMPUTE(6)
    XB_PASS(6)
    __syncthreads();
    COMPUTE(7)
    XB_PASS(7)

#undef STAGE
#undef COMPUTE
#undef XB_PASS

    // rowsum of squares; C/D layout: col = lane&15, row = 4*(lane>>4) + reg
    #pragma unroll
    for (int m = 0; m < 8; ++m) {
        #pragma unroll
        for (int r = 0; r < 4; ++r) {
            float s = 0.f;
            #pragma unroll
            for (int nt = 0; nt < 4; ++nt) { float vv = acc[m][nt][r]; s += vv * vv; }
            s += __shfl_xor(s, 1);
            s += __shfl_xor(s, 2);
            s += __shfl_xor(s, 4);
            s += __shfl_xor(s, 8);
            if (ln == 0) wpart[w][m * 16 + g * 4 + r] = s;
        }
    }

    // x.b: reduce the 4 threads sharing a row (lanes 4r..4r+3 in one wave)
    {
        float s = bacc;
        s += __shfl_xor(s, 1);
        s += __shfl_xor(s, 2);
        if ((lane & 3) == 0) bpart[t >> 2] = s;
    }
    __syncthreads();

    if (t < BM) {
        float y = c[0] + bpart[t];
        #pragma unroll
        for (int ww = 0; ww < 8; ++ww) y += wpart[ww][t];
        out[(size_t)blockIdx.x * BM + t] = y;
    }
}

extern "C" void kernel_launch(void* const* d_in, const int* in_sizes, int n_in,
                              void* d_out, int out_size, void* d_ws, size_t ws_size,
                              hipStream_t stream) {
    const float* x = (const float*)d_in[0];
    const float* L = (const float*)d_in[1];
    const float* b = (const float*)d_in[2];
    const float* c = (const float*)d_in[3];
    float* out = (float*)d_out;
    unsigned short* Ltf = (unsigned short*)d_ws;   // 512 KiB

    prep_lt<<<256, 256, 0, stream>>>(L, Ltf);
    psd_main<<<NBLOCKS, THREADS, 0, stream>>>(x, Ltf, b, c, out);
}

// Round 11
// 100.690 us; speedup vs baseline: 2.5118x; 2.4273x over previous
//
#include <hip/hip_runtime.h>
#include <stdint.h>

#define D_DIM   512
#define BM      64
#define BK      32
#define THREADS 256            // 4 waves; each wave owns 128 N-cols (nt=8)
#define NBLOCKS 2048           // 131072 / 64

typedef __attribute__((ext_vector_type(8))) __bf16 bf16x8;
typedef __attribute__((ext_vector_type(4))) float  f32x4;

__device__ __forceinline__ unsigned short f32_to_bf16_rne(float f) {
    uint32_t u = __builtin_bit_cast(uint32_t, f);
    u += 0x7FFFu + ((u >> 16) & 1u);
    return (unsigned short)(u >> 16);
}

// Repack L (fp32 row-major [K=512][N=512]) into bf16 fragment order:
// flat ushort idx = ((ks*32 + ntg)*64 + lane)*8 + e  holds L[k][n],
//   n = ntg*16 + (lane&15),  k = ks*32 + (lane>>4)*8 + e.
__global__ void prep_lt(const float* __restrict__ L, unsigned short* __restrict__ Ltf) {
    int o = blockIdx.x * 256 + threadIdx.x;
    #pragma unroll
    for (int i = 0; i < 4; ++i) {
        int idx  = o + i * 65536;
        int e    = idx & 7;
        int l    = (idx >> 3) & 63;
        int tile = idx >> 9;
        int ntg  = tile & 31;
        int ks   = tile >> 5;
        int n    = ntg * 16 + (l & 15);
        int k    = ks * 32 + (l >> 4) * 8 + e;
        Ltf[idx] = f32_to_bf16_rne(L[k * 512 + n]);
    }
}

__global__ __launch_bounds__(THREADS, 2)
void psd_main(const float* __restrict__ x, const unsigned short* __restrict__ Ltf,
              const float* __restrict__ b, const float* __restrict__ c,
              float* __restrict__ out) {
    // 3-slot fp32 ring, each slot [64 rows][32 cols] (8 KiB). Stored 16B-unit u
    // at row r holds logical unit u ^ (r&7) (involution; 8 units per 128B row).
    __shared__ __align__(16) float As[3][BM * BK];   // 24 KiB
    __shared__ __align__(16) float bsh[D_DIM];       // 2 KiB
    __shared__ float wpart[4][BM];
    __shared__ float bpart[BM];

    const int t    = threadIdx.x;
    const int w    = t >> 6;          // wave 0..3; owns n-cols [w*128, w*128+128)
    const int lane = t & 63;
    const int g    = lane >> 4;
    const int ln   = lane & 15;
    const int r8   = lane >> 3;       // stage: row sub-index (0..7)
    const int u8   = lane & 7;        // stage: stored 16B unit

    char* AsB  = (char*)&As[0][0];
    char* bshB = (char*)&bsh[0];
    const char* xB = (const char*)x + (size_t)blockIdx.x * (BM * 2048);

    // fragment-order L base for this wave (ntg = w*8 + nt)
    const unsigned short* LtW = Ltf + (size_t)w * 4096 + (size_t)lane * 8;

    f32x4 acc[4][8];
    #pragma unroll
    for (int m = 0; m < 4; ++m)
        #pragma unroll
        for (int nt = 0; nt < 8; ++nt)
            acc[m][nt] = (f32x4){0.f, 0.f, 0.f, 0.f};
    float bacc = 0.f;

    // Stage K-slice (col byte offset QOFF within each row) into slot SL.
    // Wave w covers rows [w*16, w*16+16); 2 loads/thread, linear LDS dest,
    // pre-swizzled global source (unit u8 fetches logical u8^(row&7)).
#define STAGE(QOFF, SL)                                                                  \
    {                                                                                    \
        char* ldsw = AsB + (SL) * 8192 + w * 2048;                                       \
        _Pragma("unroll")                                                                \
        for (int j = 0; j < 2; ++j) {                                                    \
            const int row = w * 16 + j * 8 + r8;                                         \
            const char* gsrc = xB + (size_t)row * 2048 + (QOFF)                          \
                             + ((u8 ^ (row & 7)) << 4);                                  \
            __builtin_amdgcn_global_load_lds(                                            \
                (const __attribute__((address_space(1))) void*)gsrc,                     \
                (__attribute__((address_space(3))) void*)(ldsw + j * 1024), 16, 0, 0);   \
        }                                                                                \
    }

    // One K-step (K=32) of MFMAs from slot pointer RB using preloaded bfr[8].
#define COMPUTE(RB)                                                                      \
    {                                                                                    \
        _Pragma("unroll")                                                                \
        for (int m = 0; m < 4; ++m) {                                                    \
            const int row = m * 16 + ln;                                                 \
            const int cb  = g * 2;                                                       \
            f32x4 f0 = *(const f32x4*)((RB) + row * 128 + (((cb    ) ^ (row & 7)) << 4));\
            f32x4 f1 = *(const f32x4*)((RB) + row * 128 + (((cb + 1) ^ (row & 7)) << 4));\
            bf16x8 a;                                                                    \
            a[0] = (__bf16)f0[0]; a[1] = (__bf16)f0[1];                                  \
            a[2] = (__bf16)f0[2]; a[3] = (__bf16)f0[3];                                  \
            a[4] = (__bf16)f1[0]; a[5] = (__bf16)f1[1];                                  \
            a[6] = (__bf16)f1[2]; a[7] = (__bf16)f1[3];                                  \
            _Pragma("unroll")                                                            \
            for (int nt = 0; nt < 8; ++nt)                                               \
                acc[m][nt] = __builtin_amdgcn_mfma_f32_16x16x32_bf16(a, bfr[nt], acc[m][nt], 0, 0, 0); \
        }                                                                                \
    }

    // x.b partial: thread covers row t>>2, units (t&3)*2 .. +1; b from LDS.
#define XB(RB, BOFF)                                                                     \
    {                                                                                    \
        const int row = t >> 2;                                                          \
        const int rsw = row & 7;                                                         \
        _Pragma("unroll")                                                                \
        for (int i = 0; i < 2; ++i) {                                                    \
            const int unit = (t & 3) * 2 + i;                                            \
            f32x4 xv = *(const f32x4*)((RB) + row * 128 + ((unit ^ rsw) << 4));          \
            f32x4 bv = *(const f32x4*)(bshB + (BOFF) + unit * 16);                       \
            bacc += xv[0] * bv[0] + xv[1] * bv[1] + xv[2] * bv[2] + xv[3] * bv[3];       \
        }                                                                                \
    }

    // ---- prologue: b first (oldest), then slices 0,1 ----
    if (t < 128) {
        const char* gsrc = (const char*)b + (size_t)t * 16;
        __builtin_amdgcn_global_load_lds(
            (const __attribute__((address_space(1))) void*)gsrc,
            (__attribute__((address_space(3))) void*)(bshB + t * 16), 16, 0, 0);
    }
    STAGE(0, 0)
    STAGE(128, 1)
    asm volatile("s_waitcnt vmcnt(2)" ::: "memory");   // b + slice0 done; slice1 in flight
    __builtin_amdgcn_s_barrier();

    // ---- main loop: steps 0..13, each stages slice q+2 ----
    int sl   = 0;                 // compute slot
    int qoff = 2 * 128;           // stage col byte offset (slice q+2)
    int boff = 0;                 // b byte offset for XB
    const unsigned short* Lp = LtW;

    #pragma unroll 1
    for (int q = 0; q < 14; ++q) {
        // B-fragments first (oldest VMEM) so their waits never drain the stage loads
        bf16x8 bfr[8];
        #pragma unroll
        for (int nt = 0; nt < 8; ++nt)
            bfr[nt] = *(const bf16x8*)(Lp + nt * 512);
        __builtin_amdgcn_sched_barrier(0);

        int sls = sl + 2; if (sls >= 3) sls -= 3;
        STAGE(qoff, sls)

        const char* rb = AsB + sl * 8192;
        COMPUTE(rb)
        XB(rb, boff)

        asm volatile("s_waitcnt lgkmcnt(0)" ::: "memory");  // my ds_reads done pre-barrier
        asm volatile("s_waitcnt vmcnt(2)" ::: "memory");    // slice q+1 landed; q+2 in flight
        __builtin_amdgcn_s_barrier();

        if (++sl == 3) sl = 0;
        qoff += 128;
        boff += 128;
        Lp   += 16384;
    }

    // ---- step 14: compute slot 2, no stage; drain slice 15 fully ----
    {
        bf16x8 bfr[8];
        #pragma unroll
        for (int nt = 0; nt < 8; ++nt)
            bfr[nt] = *(const bf16x8*)(Lp + nt * 512);
        const char* rb = AsB + 2 * 8192;
        COMPUTE(rb)
        XB(rb, 14 * 128)
        asm volatile("s_waitcnt lgkmcnt(0)" ::: "memory");
        asm volatile("s_waitcnt vmcnt(0)" ::: "memory");
        __builtin_amdgcn_s_barrier();
    }
    // ---- step 15: compute slot 0 ----
    {
        bf16x8 bfr[8];
        #pragma unroll
        for (int nt = 0; nt < 8; ++nt)
            bfr[nt] = *(const bf16x8*)(Lp + 16384 + nt * 512);
        const char* rb = AsB;
        COMPUTE(rb)
        XB(rb, 15 * 128)
    }

#undef STAGE
#undef COMPUTE
#undef XB

    // rowsum of squares; C/D layout: col = lane&15, row = 4*(lane>>4) + reg
    #pragma unroll
    for (int m = 0; m < 4; ++m) {
        #pragma unroll
        for (int r = 0; r < 4; ++r) {
            float s = 0.f;
            #pragma unroll
            for (int nt = 0; nt < 8; ++nt) { float vv = acc[m][nt][r]; s += vv * vv; }
            s += __shfl_xor(s, 1);
            s += __shfl_xor(s, 2);
            s += __shfl_xor(s, 4);
            s += __shfl_xor(s, 8);
            if (ln == 0) wpart[w][m * 16 + g * 4 + r] = s;
        }
    }

    // x.b: reduce the 4 threads sharing a row (lane bits 0..1)
    {
        float s = bacc;
        s += __shfl_xor(s, 1);
        s += __shfl_xor(s, 2);
        if ((lane & 3) == 0) bpart[t >> 2] = s;
    }
    __syncthreads();

    if (t < BM) {
        float y = c[0] + bpart[t]
                + wpart[0][t] + wpart[1][t] + wpart[2][t] + wpart[3][t];
        out[(size_t)blockIdx.x * BM + t] = y;
    }
}

extern "C" void kernel_launch(void* const* d_in, const int* in_sizes, int n_in,
                              void* d_out, int out_size, void* d_ws, size_t ws_size,
                              hipStream_t stream) {
    const float* x = (const float*)d_in[0];
    const float* L = (const float*)d_in[1];
    const float* b = (const float*)d_in[2];
    const float* c = (const float*)d_in[3];
    float* out = (float*)d_out;
    unsigned short* Ltf = (unsigned short*)d_ws;   // 512 KiB

    prep_lt<<<256, 256, 0, stream>>>(L, Ltf);
    psd_main<<<NBLOCKS, THREADS, 0, stream>>>(x, Ltf, b, c, out);
}